// Round 2
// baseline (1245.816 us; speedup 1.0000x reference)
//
#include <hip/hip_runtime.h>
#include <hip/hip_bf16.h>

#define L_SEQ 32
#define DIM 128
#define NN 50000

// ---------- helpers ----------
__device__ __forceinline__ void ldf8(const float* p, float* w){
    const float4 a = *reinterpret_cast<const float4*>(p);
    const float4 b = *reinterpret_cast<const float4*>(p+4);
    w[0]=a.x; w[1]=a.y; w[2]=a.z; w[3]=a.w;
    w[4]=b.x; w[5]=b.y; w[6]=b.z; w[7]=b.w;
}
__device__ __forceinline__ float sigmoidf(float x){ return 1.0f/(1.0f+__expf(-x)); }
__device__ __forceinline__ float tanh_fast(float x){
    x = fminf(fmaxf(x, -15.f), 15.f);
    float e = __expf(2.f*x);
    return (e-1.f)/(e+1.f);
}

// ---------- weight transpose (f32, dst-major so writes coalesce) ----------
// WT element offsets (floats):
// WinT 0 [128][128] | WoutT 16384 | WaT 32768 [384][256] | UhT 131072 [384][128]
// WiT 180224 | WhT 229376 | W1T 278528 | W2T 294912 | W3T 311296 [128][256]  total 344064
__global__ __launch_bounds__(256)
void transp_kernel(const float* __restrict__ W_in, const float* __restrict__ W_out,
                   const float* __restrict__ W_a,  const float* __restrict__ U_h,
                   const float* __restrict__ Wi,   const float* __restrict__ Wh,
                   const float* __restrict__ W1,   const float* __restrict__ W2,
                   const float* __restrict__ W3,   float* __restrict__ wt)
{
    int idx = blockIdx.x*256 + threadIdx.x;
    const float* src; int Rm1, lR, C, local, off;
    if      (idx < 16384) { src=W_in;  local=idx;        off=0;      Rm1=127; lR=7; C=128; }
    else if (idx < 32768) { src=W_out; local=idx-16384;  off=16384;  Rm1=127; lR=7; C=128; }
    else if (idx < 131072){ src=W_a;   local=idx-32768;  off=32768;  Rm1=255; lR=8; C=384; }
    else if (idx < 180224){ src=U_h;   local=idx-131072; off=131072; Rm1=127; lR=7; C=384; }
    else if (idx < 229376){ src=Wi;    local=idx-180224; off=180224; Rm1=127; lR=7; C=384; }
    else if (idx < 278528){ src=Wh;    local=idx-229376; off=229376; Rm1=127; lR=7; C=384; }
    else if (idx < 294912){ src=W1;    local=idx-278528; off=278528; Rm1=127; lR=7; C=128; }
    else if (idx < 311296){ src=W2;    local=idx-294912; off=294912; Rm1=127; lR=7; C=128; }
    else if (idx < 344064){ src=W3;    local=idx-311296; off=311296; Rm1=255; lR=8; C=128; }
    else return;
    int r = local & Rm1;
    int c = local >> lR;
    wt[off + local] = src[r*C + c];
}

// ---------- fused graph kernel: one block per session ----------
__global__ __launch_bounds__(256)
void graph_fused(const int* __restrict__ items,
                 const float* __restrict__ A_in, const float* __restrict__ A_out,
                 const float* __restrict__ inter,
                 const int* __restrict__ seq_len,
                 const float* __restrict__ emb,
                 const float* __restrict__ b_in, const float* __restrict__ b_out,
                 const float* __restrict__ b_gru,
                 const float* __restrict__ bi, const float* __restrict__ bh,
                 const float* __restrict__ b1, const float* __restrict__ b2,
                 const float* __restrict__ wq, const float* __restrict__ bq,
                 const float* __restrict__ b3,
                 const float* __restrict__ WT,
                 float* __restrict__ hs_out)
{
    const float* WinT  = WT + 0;
    const float* WoutT = WT + 16384;
    const float* WaT   = WT + 32768;
    const float* UhT   = WT + 131072;
    const float* WiT   = WT + 180224;
    const float* WhT   = WT + 229376;
    const float* W1T   = WT + 278528;
    const float* W2T   = WT + 294912;
    const float* W3T   = WT + 311296;

    __shared__ float s_h[L_SEQ][DIM];     // h -> inter
    __shared__ float s_x[L_SEQ][DIM];     // hin -> hout -> intra
    __shared__ float s_a[L_SEQ][260];     // concat(a_in,a_out) -> final (cols 0..127); pad kills bank conflicts
    __shared__ float s_A[2][L_SEQ][L_SEQ];
    __shared__ int   s_items[L_SEQ];
    __shared__ float s_vn[DIM], s_q1[DIM], s_red[L_SEQ][8], s_alpha[L_SEQ], s_sg[DIM];

    const int b  = blockIdx.x;
    const int t  = threadIdx.x;
    const int j  = t & 127;
    const int lh = t >> 7;          // 0/1 -> rows lh*16 .. lh*16+15

    if (t < L_SEQ) s_items[t] = items[b*L_SEQ + t];
    {   // adjacency tiles: 2*1024 f32, 8 per thread
        const int which = t >> 7;
        const int rem   = t & 127;
        const int l = rem >> 2, m = (rem & 3) * 8;
        const float* src = which ? A_out : A_in;
        float v[8]; ldf8(src + b*L_SEQ*L_SEQ + l*L_SEQ + m, v);
        #pragma unroll
        for (int u=0;u<8;++u) s_A[which][l][m+u] = v[u];
    }
    __syncthreads();

    // ---- gather h = emb_table[items]
    #pragma unroll
    for (int i=0;i<2;++i) {
        int c = t + i*256;                  // 512 chunks of 8
        int l = c >> 4, k = (c & 15) * 8;
        float v[8]; ldf8(emb + (size_t)s_items[l]*DIM + k, v);
        #pragma unroll
        for (int u=0;u<8;++u) s_h[l][k+u] = v[u];
    }
    __syncthreads();

    // ---- hin = h @ W_in + b_in -> s_x
    {
        float acc[16];
        const float bv = b_in[j];
        #pragma unroll
        for (int i=0;i<16;++i) acc[i]=bv;
        for (int k0=0;k0<DIM;k0+=8) {
            float w[8]; ldf8(WinT + j*DIM + k0, w);
            #pragma unroll
            for (int i=0;i<16;++i) {
                const float* hr = &s_h[lh*16+i][k0];
                #pragma unroll
                for (int u=0;u<8;++u) acc[i] += hr[u]*w[u];
            }
        }
        #pragma unroll
        for (int i=0;i<16;++i) s_x[lh*16+i][j] = acc[i];
    }
    __syncthreads();
    // ---- a_in = A_in @ hin -> s_a[:,0:128]
    {
        float acc[16] = {};
        for (int m0=0;m0<L_SEQ;m0+=4) {
            float xv[4];
            #pragma unroll
            for (int u=0;u<4;++u) xv[u] = s_x[m0+u][j];
            #pragma unroll
            for (int i=0;i<16;++i) {
                const float* Ar = &s_A[0][lh*16+i][m0];
                #pragma unroll
                for (int u=0;u<4;++u) acc[i] += Ar[u]*xv[u];
            }
        }
        #pragma unroll
        for (int i=0;i<16;++i) s_a[lh*16+i][j] = acc[i];
    }
    __syncthreads();
    // ---- hout = h @ W_out + b_out -> s_x
    {
        float acc[16];
        const float bv = b_out[j];
        #pragma unroll
        for (int i=0;i<16;++i) acc[i]=bv;
        for (int k0=0;k0<DIM;k0+=8) {
            float w[8]; ldf8(WoutT + j*DIM + k0, w);
            #pragma unroll
            for (int i=0;i<16;++i) {
                const float* hr = &s_h[lh*16+i][k0];
                #pragma unroll
                for (int u=0;u<8;++u) acc[i] += hr[u]*w[u];
            }
        }
        #pragma unroll
        for (int i=0;i<16;++i) s_x[lh*16+i][j] = acc[i];
    }
    __syncthreads();
    // ---- a_out = A_out @ hout -> s_a[:,128:256]
    {
        float acc[16] = {};
        for (int m0=0;m0<L_SEQ;m0+=4) {
            float xv[4];
            #pragma unroll
            for (int u=0;u<4;++u) xv[u] = s_x[m0+u][j];
            #pragma unroll
            for (int i=0;i<16;++i) {
                const float* Ar = &s_A[1][lh*16+i][m0];
                #pragma unroll
                for (int u=0;u<4;++u) acc[i] += Ar[u]*xv[u];
            }
        }
        #pragma unroll
        for (int i=0;i<16;++i) s_a[lh*16+i][128+j] = acc[i];
    }
    __syncthreads();

    // ---- intra = GRU(a @ W_a + b_gru, h @ U_h ; h) -> s_x
    {
        const float bgr = b_gru[j];
        const float bgz = b_gru[j+128];
        const float bgn = b_gru[j+256];
        #pragma unroll
        for (int half=0; half<2; ++half) {
            const int lbase = lh*16 + half*8;
            float ar[8], az[8], an[8];
            #pragma unroll
            for (int i=0;i<8;++i){ ar[i]=bgr; az[i]=bgz; an[i]=bgn; }
            for (int k0=0;k0<2*DIM;k0+=8) {
                float wr[8], wz[8], wn[8];
                ldf8(WaT + (j      )*256 + k0, wr);
                ldf8(WaT + (j + 128)*256 + k0, wz);
                ldf8(WaT + (j + 256)*256 + k0, wn);
                #pragma unroll
                for (int i=0;i<8;++i) {
                    const float* av = &s_a[lbase+i][k0];
                    #pragma unroll
                    for (int u=0;u<8;++u){ ar[i]+=av[u]*wr[u]; az[i]+=av[u]*wz[u]; an[i]+=av[u]*wn[u]; }
                }
            }
            float hr[8], hz[8], hn[8];
            #pragma unroll
            for (int i=0;i<8;++i){ hr[i]=0.f; hz[i]=0.f; hn[i]=0.f; }
            for (int k0=0;k0<DIM;k0+=8) {
                float wr[8], wz[8], wn[8];
                ldf8(UhT + (j      )*DIM + k0, wr);
                ldf8(UhT + (j + 128)*DIM + k0, wz);
                ldf8(UhT + (j + 256)*DIM + k0, wn);
                #pragma unroll
                for (int i=0;i<8;++i) {
                    const float* hv = &s_h[lbase+i][k0];
                    #pragma unroll
                    for (int u=0;u<8;++u){ hr[i]+=hv[u]*wr[u]; hz[i]+=hv[u]*wz[u]; hn[i]+=hv[u]*wn[u]; }
                }
            }
            #pragma unroll
            for (int i=0;i<8;++i) {
                const int l = lbase+i;
                float r = sigmoidf(ar[i]+hr[i]);
                float z = sigmoidf(az[i]+hz[i]);
                float n = tanh_fast(an[i] + r*hn[i]);
                float hp = s_h[l][j];
                s_x[l][j] = (1.f - z)*n + z*hp;
            }
        }
    }
    __syncthreads();

    // ---- load inter_item_emb -> s_h
    #pragma unroll
    for (int i=0;i<2;++i) {
        int c = t + i*256;
        int l = c >> 4, k = (c & 15) * 8;
        float v[8]; ldf8(inter + ((size_t)b*L_SEQ + l)*DIM + k, v);
        #pragma unroll
        for (int u=0;u<8;++u) s_h[l][k+u] = v[u];
    }
    __syncthreads();

    // ---- final = GRU(intra @ Wi + bi, inter @ Wh + bh ; inter) -> s_a[:,0:128]
    {
        const float bir = bi[j];
        const float biz = bi[j+128];
        const float bin_ = bi[j+256];
        const float bhr = bh[j];
        const float bhz = bh[j+128];
        const float bhn = bh[j+256];
        #pragma unroll
        for (int half=0; half<2; ++half) {
            const int lbase = lh*16 + half*8;
            float ar[8], az[8], an[8];
            #pragma unroll
            for (int i=0;i<8;++i){ ar[i]=bir; az[i]=biz; an[i]=bin_; }
            for (int k0=0;k0<DIM;k0+=8) {
                float wr[8], wz[8], wn[8];
                ldf8(WiT + (j      )*DIM + k0, wr);
                ldf8(WiT + (j + 128)*DIM + k0, wz);
                ldf8(WiT + (j + 256)*DIM + k0, wn);
                #pragma unroll
                for (int i=0;i<8;++i) {
                    const float* xv = &s_x[lbase+i][k0];
                    #pragma unroll
                    for (int u=0;u<8;++u){ ar[i]+=xv[u]*wr[u]; az[i]+=xv[u]*wz[u]; an[i]+=xv[u]*wn[u]; }
                }
            }
            float hr[8], hz[8], hn[8];
            #pragma unroll
            for (int i=0;i<8;++i){ hr[i]=bhr; hz[i]=bhz; hn[i]=bhn; }
            for (int k0=0;k0<DIM;k0+=8) {
                float wr[8], wz[8], wn[8];
                ldf8(WhT + (j      )*DIM + k0, wr);
                ldf8(WhT + (j + 128)*DIM + k0, wz);
                ldf8(WhT + (j + 256)*DIM + k0, wn);
                #pragma unroll
                for (int i=0;i<8;++i) {
                    const float* hv = &s_h[lbase+i][k0];
                    #pragma unroll
                    for (int u=0;u<8;++u){ hr[i]+=hv[u]*wr[u]; hz[i]+=hv[u]*wz[u]; hn[i]+=hv[u]*wn[u]; }
                }
            }
            #pragma unroll
            for (int i=0;i<8;++i) {
                const int l = lbase+i;
                float r = sigmoidf(ar[i]+hr[i]);
                float z = sigmoidf(az[i]+hz[i]);
                float n = tanh_fast(an[i] + r*hn[i]);
                float hp = s_h[l][j];
                s_a[l][j] = (1.f - z)*n + z*hp;
            }
        }
    }
    __syncthreads();

    // ---- attention readout
    const int slen = seq_len[b];
    if (t < DIM) s_vn[t] = s_a[slen-1][t];
    __syncthreads();
    if (t < DIM) {                      // q1 = v_n @ W1 + b1
        float acc = b1[t];
        for (int k0=0;k0<DIM;k0+=8) {
            float w[8]; ldf8(W1T + t*DIM + k0, w);
            #pragma unroll
            for (int u=0;u<8;++u) acc += s_vn[k0+u]*w[u];
        }
        s_q1[t] = acc;
    }
    __syncthreads();
    {   // alpha[l] = sum_j sigmoid(q1[j] + final[l]@W2[:,j] + b2[j]) * wq[j]
        const int lq  = t >> 3;
        const int sub = t & 7;
        float part = 0.f;
        #pragma unroll
        for (int jj=0; jj<16; ++jj) {
            const int j2 = sub*16 + jj;
            float acc = s_q1[j2] + b2[j2];
            for (int k0=0;k0<DIM;k0+=8) {
                float w[8]; ldf8(W2T + j2*DIM + k0, w);
                const float* fv = &s_a[lq][k0];
                #pragma unroll
                for (int u=0;u<8;++u) acc += fv[u]*w[u];
            }
            part += sigmoidf(acc) * wq[j2];
        }
        s_red[lq][sub] = part;
    }
    __syncthreads();
    if (t < L_SEQ) {
        float al = 0.f;
        #pragma unroll
        for (int u=0;u<8;++u) al += s_red[t][u];
        al += bq[0];
        s_alpha[t] = (t < slen) ? al : 0.f;
    }
    __syncthreads();
    if (t < DIM) {                      // s_g = sum_l alpha[l]*final[l]
        float sg = 0.f;
        #pragma unroll
        for (int l=0;l<L_SEQ;++l) sg += s_alpha[l]*s_a[l][t];
        s_sg[t] = sg;
    }
    __syncthreads();
    if (t < DIM) {                      // h_s = concat(vn, sg) @ W3 + b3
        float acc = b3[t];
        for (int k0=0;k0<DIM;k0+=8) {
            float w[8];  ldf8(W3T + t*256 + k0, w);
            #pragma unroll
            for (int u=0;u<8;++u) acc += s_vn[k0+u]*w[u];
            float w2[8]; ldf8(W3T + t*256 + 128 + k0, w2);
            #pragma unroll
            for (int u=0;u<8;++u) acc += s_sg[k0+u]*w2[u];
        }
        hs_out[b*DIM + t] = acc;
    }
}

// ---------- scores = h_s @ emb^T : 64x64 tile per block ----------
__global__ __launch_bounds__(256)
void scores_kernel(const float* __restrict__ hs, const float* __restrict__ emb,
                   float* __restrict__ out)
{
    __shared__ float s_hs[64][DIM];     // 32 KB
    __shared__ float s_embT[DIM][65];   // 33 KB, transposed+padded
    const int t  = threadIdx.x;
    const int n0 = blockIdx.x * 64;
    const int m0 = blockIdx.y * 64;
    {
        const float4* src = reinterpret_cast<const float4*>(hs + m0*DIM);
        float4* dst = reinterpret_cast<float4*>(&s_hs[0][0]);
        #pragma unroll
        for (int i=0;i<8;++i) dst[t + i*256] = src[t + i*256];
    }
    #pragma unroll
    for (int i=0;i<4;++i) {
        int c = t + i*256;              // 1024 chunks of 8
        int n = c >> 4, k0 = (c & 15)*8;
        float v[8];
        if (n0 + n < NN) ldf8(emb + (size_t)(n0+n)*DIM + k0, v);
        else {
            #pragma unroll
            for (int u=0;u<8;++u) v[u]=0.f;
        }
        #pragma unroll
        for (int u=0;u<8;++u) s_embT[k0+u][n] = v[u];
    }
    __syncthreads();

    const int nh = t & 31;              // columns 2*nh, 2*nh+1
    const int mq = t >> 5;              // rows mq*8 .. mq*8+7
    float acc0[8] = {}, acc1[8] = {};
    for (int k0=0;k0<DIM;k0+=4) {
        float e0[4], e1[4];
        #pragma unroll
        for (int u=0;u<4;++u){ e0[u]=s_embT[k0+u][2*nh]; e1[u]=s_embT[k0+u][2*nh+1]; }
        #pragma unroll
        for (int i=0;i<8;++i) {
            const float* hp = &s_hs[mq*8+i][k0];
            #pragma unroll
            for (int u=0;u<4;++u){ acc0[i]+=hp[u]*e0[u]; acc1[i]+=hp[u]*e1[u]; }
        }
    }
    const int n = n0 + 2*nh;
    if (n < NN) {
        #pragma unroll
        for (int i=0;i<8;++i) {
            const int m = m0 + mq*8 + i;
            float2 v; v.x = acc0[i]; v.y = acc1[i];
            *reinterpret_cast<float2*>(out + (size_t)m*NN + n) = v;
        }
    }
}

extern "C" void kernel_launch(void* const* d_in, const int* in_sizes, int n_in,
                              void* d_out, int out_size, void* d_ws, size_t ws_size,
                              hipStream_t stream)
{
    const int*   items   = (const int*)  d_in[0];
    const float* A_in    = (const float*)d_in[1];
    const float* A_out   = (const float*)d_in[2];
    const float* inter   = (const float*)d_in[3];
    const int*   seq_len = (const int*)  d_in[4];
    const float* emb     = (const float*)d_in[5];
    const float* W_in = (const float*)d_in[6],  *b_in  = (const float*)d_in[7];
    const float* W_out= (const float*)d_in[8],  *b_out = (const float*)d_in[9];
    const float* W_a  = (const float*)d_in[10], *U_h   = (const float*)d_in[11];
    const float* b_gru= (const float*)d_in[12];
    const float* Wi   = (const float*)d_in[13], *bi    = (const float*)d_in[14];
    const float* Wh   = (const float*)d_in[15], *bh    = (const float*)d_in[16];
    const float* W1   = (const float*)d_in[17], *b1    = (const float*)d_in[18];
    const float* W2   = (const float*)d_in[19], *b2    = (const float*)d_in[20];
    const float* wq   = (const float*)d_in[21], *bq    = (const float*)d_in[22];
    const float* W3   = (const float*)d_in[23], *b3    = (const float*)d_in[24];
    float* out = (float*)d_out;
    float* hs  = (float*)d_ws;                                  // 1024*128 f32
    float* wt  = (float*)((char*)d_ws + 1024*128*4);            // 344064 f32

    transp_kernel<<<1344, 256, 0, stream>>>(W_in, W_out, W_a, U_h, Wi, Wh, W1, W2, W3, wt);
    graph_fused<<<1024, 256, 0, stream>>>(items, A_in, A_out, inter, seq_len, emb,
        b_in, b_out, b_gru, bi, bh, b1, b2, wq, bq, b3, wt, hs);
    scores_kernel<<<dim3(782, 16), 256, 0, stream>>>(hs, emb, out);
}

// Round 3
// 566.950 us; speedup vs baseline: 2.1974x; 2.1974x over previous
//
#include <hip/hip_runtime.h>
#include <hip/hip_bf16.h>

#define L_SEQ 32
#define DIM 128
#define NN 50000

typedef __attribute__((ext_vector_type(8))) short bf16x8s;
typedef __attribute__((ext_vector_type(4))) float f32x4;

// ---------- helpers ----------
__device__ __forceinline__ float bf2f(short s){
    union{unsigned u; float f;} v; v.u = ((unsigned)(unsigned short)s) << 16; return v.f;
}
__device__ __forceinline__ short f2bf(float x){
    union{__hip_bfloat16 h; short s;} u; u.h = __float2bfloat16(x); return u.s;
}
__device__ __forceinline__ void ldf8(const float* p, float* w){
    const float4 a = *reinterpret_cast<const float4*>(p);
    const float4 b = *reinterpret_cast<const float4*>(p+4);
    w[0]=a.x; w[1]=a.y; w[2]=a.z; w[3]=a.w;
    w[4]=b.x; w[5]=b.y; w[6]=b.z; w[7]=b.w;
}
__device__ __forceinline__ void st8bf(short* dst, const float* v){
    union{ short s[8]; uint4 q; } u;
    #pragma unroll
    for (int i=0;i<8;++i) u.s[i] = f2bf(v[i]);
    *reinterpret_cast<uint4*>(dst) = u.q;
}
__device__ __forceinline__ bf16x8s cvt8(const float* v){
    union{ short s[8]; bf16x8s b; } u;
    #pragma unroll
    for (int i=0;i<8;++i) u.s[i] = f2bf(v[i]);
    return u.b;
}
__device__ __forceinline__ float sigmoidf(float x){ return 1.0f/(1.0f+__expf(-x)); }
__device__ __forceinline__ float tanh_fast(float x){
    x = fminf(fmaxf(x, -15.f), 15.f);
    float e = __expf(2.f*x);
    return (e-1.f)/(e+1.f);
}
__device__ __forceinline__ f32x4 mfma16(bf16x8s a, bf16x8s b, f32x4 c){
    return __builtin_amdgcn_mfma_f32_16x16x32_bf16(a, b, c, 0, 0, 0);
}

// ---------- weight transpose -> bf16, dst layout [n][k] k-contiguous ----------
// element offsets: WinT 0 [128][128] | WoutT 16384 | WaT 32768 [384][256] |
// UhT 131072 [384][128] | WiT 180224 | WhT 229376 | W1T 278528 | W2T 294912 |
// W3T 311296 [128][256]   total 344064
__global__ __launch_bounds__(256)
void transp_kernel(const float* __restrict__ W_in, const float* __restrict__ W_out,
                   const float* __restrict__ W_a,  const float* __restrict__ U_h,
                   const float* __restrict__ Wi,   const float* __restrict__ Wh,
                   const float* __restrict__ W1,   const float* __restrict__ W2,
                   const float* __restrict__ W3,   short* __restrict__ wt)
{
    int idx = blockIdx.x*256 + threadIdx.x;
    const float* src; int Rm1, lR, C, local, off;
    if      (idx < 16384) { src=W_in;  local=idx;        off=0;      Rm1=127; lR=7; C=128; }
    else if (idx < 32768) { src=W_out; local=idx-16384;  off=16384;  Rm1=127; lR=7; C=128; }
    else if (idx < 131072){ src=W_a;   local=idx-32768;  off=32768;  Rm1=255; lR=8; C=384; }
    else if (idx < 180224){ src=U_h;   local=idx-131072; off=131072; Rm1=127; lR=7; C=384; }
    else if (idx < 229376){ src=Wi;    local=idx-180224; off=180224; Rm1=127; lR=7; C=384; }
    else if (idx < 278528){ src=Wh;    local=idx-229376; off=229376; Rm1=127; lR=7; C=384; }
    else if (idx < 294912){ src=W1;    local=idx-278528; off=278528; Rm1=127; lR=7; C=128; }
    else if (idx < 311296){ src=W2;    local=idx-294912; off=294912; Rm1=127; lR=7; C=128; }
    else if (idx < 344064){ src=W3;    local=idx-311296; off=311296; Rm1=255; lR=8; C=128; }
    else return;
    int r = local & Rm1;      // k (dst inner)
    int c = local >> lR;      // n (dst row)
    wt[off + local] = f2bf(src[r*C + c]);
}

// ---------- fused graph kernel: one block (4 waves) per session, MFMA ----------
#define LDH 136   // 128-wide bf16 rows, +8 pad
#define LDA 264   // 256-wide
#define LDT 40    // transposed k<=32 rows

__global__ __launch_bounds__(256)
void graph_fused(const int* __restrict__ items,
                 const float* __restrict__ A_in, const float* __restrict__ A_out,
                 const float* __restrict__ inter,
                 const int* __restrict__ seq_len,
                 const float* __restrict__ emb,
                 const float* __restrict__ b_in, const float* __restrict__ b_out,
                 const float* __restrict__ b_gru,
                 const float* __restrict__ bi, const float* __restrict__ bh,
                 const float* __restrict__ b1, const float* __restrict__ b2,
                 const float* __restrict__ wq, const float* __restrict__ bq,
                 const float* __restrict__ b3,
                 const short* __restrict__ wt,
                 short* __restrict__ hs_bf)
{
    const short* WinT  = wt + 0;
    const short* WoutT = wt + 16384;
    const short* WaT   = wt + 32768;
    const short* UhT   = wt + 131072;
    const short* WiT   = wt + 180224;
    const short* WhT   = wt + 229376;
    const short* W1T   = wt + 278528;
    const short* W2T   = wt + 294912;
    const short* W3T   = wt + 311296;

    __shared__ __align__(16) short s_h[32*LDH];        // h (bf16, A-layout)
    __shared__ __align__(16) short s_a[32*LDA];        // concat(a_in,a_out)
    __shared__ __align__(16) short s_r3[32*LDH];       // {Ain,Aout} then intra
    __shared__ __align__(16) short s_r4[2*128*LDT];    // {hinT,houtT} then {inter,final}
    __shared__ float s_vn[DIM], s_q1[DIM], s_sg[DIM], s_red[32*8], s_alpha[32];

    short* s_Ain  = s_r3;               // 32*40
    short* s_Aout = s_r3 + 32*LDT;      // 32*40
    short* s_x    = s_r3;               // intra, 32*136 (after step2)
    short* xT1    = s_r4;               // 128*40
    short* xT2    = s_r4 + 128*LDT;     // 128*40
    short* s_int  = s_r4;               // inter, 32*136 (after step2)
    short* s_fin  = s_r4 + 32*LDH;      // final, 32*136 (after step2)

    const int b    = blockIdx.x;
    const int t    = threadIdx.x;
    const int wave = t >> 6;
    const int lane = t & 63;
    const int quad = lane >> 4;
    const int lc   = lane & 15;
    const int kq   = quad * 8;

    // ---- step0: load h (gather), A_in/A_out -> bf16 LDS
    #pragma unroll
    for (int i=0;i<2;++i) {
        int c = t + i*256;                 // 512 chunks of 8
        int l = c >> 4, k = (c & 15) * 8;
        int it = items[b*L_SEQ + l];
        float v[8]; ldf8(emb + (size_t)it*DIM + k, v);
        st8bf(&s_h[l*LDH + k], v);
    }
    {
        const int which = t >> 7;
        const int rem   = t & 127;
        const int l = rem >> 2, m = (rem & 3) * 8;
        const float* src = which ? A_out : A_in;
        float v[8]; ldf8(src + b*L_SEQ*L_SEQ + l*L_SEQ + m, v);
        st8bf((which ? s_Aout : s_Ain) + l*LDT + m, v);
    }
    __syncthreads();

    // ---- step1: hin = h@W_in + b_in -> xT1[n][k];  hout -> xT2
    #pragma unroll
    for (int p = 0; p < 2; ++p) {
        const int nt = wave*2 + p;
        const int n  = nt*16 + lc;
        #pragma unroll
        for (int op = 0; op < 2; ++op) {
            const short* WT_ = op ? WoutT : WinT;
            const float  bv  = op ? b_out[n] : b_in[n];
            f32x4 acc0 = {bv,bv,bv,bv}, acc1 = {bv,bv,bv,bv};
            #pragma unroll
            for (int ks = 0; ks < 4; ++ks) {
                const int ko = ks*32 + kq;
                bf16x8s bb = *(const bf16x8s*)(WT_ + n*128 + ko);
                bf16x8s a0 = *(const bf16x8s*)(&s_h[(lc   )*LDH + ko]);
                bf16x8s a1 = *(const bf16x8s*)(&s_h[(16+lc)*LDH + ko]);
                acc0 = mfma16(a0, bb, acc0);
                acc1 = mfma16(a1, bb, acc1);
            }
            short* xT = op ? xT2 : xT1;
            union{short s[4]; unsigned long long q;} u0, u1;
            #pragma unroll
            for (int i=0;i<4;++i){ u0.s[i]=f2bf(acc0[i]); u1.s[i]=f2bf(acc1[i]); }
            *(unsigned long long*)(&xT[n*LDT + 0  + quad*4]) = u0.q;
            *(unsigned long long*)(&xT[n*LDT + 16 + quad*4]) = u1.q;
        }
    }
    __syncthreads();

    // ---- step2: a_in = A_in@hin, a_out = A_out@hout -> s_a (K=32, one MFMA)
    #pragma unroll
    for (int u = 0; u < 8; ++u) {
        int unit  = wave*8 + u;            // 0..31
        int which = unit >> 4;
        int rest  = unit & 15;
        int nt = rest >> 1, m0 = (rest & 1)*16;
        const short* Abuf = which ? s_Aout : s_Ain;
        const short* xT   = which ? xT2 : xT1;
        bf16x8s a  = *(const bf16x8s*)(&Abuf[(m0+lc)*LDT + kq]);
        bf16x8s bb = *(const bf16x8s*)(&xT[(nt*16+lc)*LDT + kq]);
        f32x4 acc = {0.f,0.f,0.f,0.f};
        acc = mfma16(a, bb, acc);
        #pragma unroll
        for (int i=0;i<4;++i)
            s_a[(m0+quad*4+i)*LDA + which*128 + nt*16 + lc] = f2bf(acc[i]);
    }
    __syncthreads();

    // ---- step3: load inter -> s_int (overwrites xT1 region; xT2 dead)
    #pragma unroll
    for (int i=0;i<2;++i) {
        int c = t + i*256;
        int l = c >> 4, k = (c & 15) * 8;
        float v[8]; ldf8(inter + ((size_t)b*L_SEQ + l)*DIM + k, v);
        st8bf(&s_int[l*LDH + k], v);
    }

    // ---- step4: intra = GRU(a@W_a + b_gru, h@U_h ; h) -> s_x
    #pragma unroll
    for (int g = wave; g < 8; g += 4) {
        const int n = g*16 + lc;
        const float vr = b_gru[n], vz = b_gru[128+n], vn2 = b_gru[256+n];
        f32x4 ar[2], az[2], an[2], pr[2], pz[2], pn[2];
        #pragma unroll
        for (int m=0;m<2;++m){
            ar[m]=(f32x4){vr,vr,vr,vr}; az[m]=(f32x4){vz,vz,vz,vz}; an[m]=(f32x4){vn2,vn2,vn2,vn2};
            pr[m]=(f32x4){0,0,0,0}; pz[m]=pr[m]; pn[m]=pr[m];
        }
        #pragma unroll
        for (int ks=0; ks<8; ++ks) {
            const int ko = ks*32 + kq;
            bf16x8s br = *(const bf16x8s*)(WaT + (n      )*256 + ko);
            bf16x8s bz = *(const bf16x8s*)(WaT + (n + 128)*256 + ko);
            bf16x8s bn = *(const bf16x8s*)(WaT + (n + 256)*256 + ko);
            #pragma unroll
            for (int m=0;m<2;++m){
                bf16x8s a = *(const bf16x8s*)(&s_a[(m*16+lc)*LDA + ko]);
                ar[m]=mfma16(a,br,ar[m]); az[m]=mfma16(a,bz,az[m]); an[m]=mfma16(a,bn,an[m]);
            }
        }
        #pragma unroll
        for (int ks=0; ks<4; ++ks) {
            const int ko = ks*32 + kq;
            bf16x8s br = *(const bf16x8s*)(UhT + (n      )*128 + ko);
            bf16x8s bz = *(const bf16x8s*)(UhT + (n + 128)*128 + ko);
            bf16x8s bn = *(const bf16x8s*)(UhT + (n + 256)*128 + ko);
            #pragma unroll
            for (int m=0;m<2;++m){
                bf16x8s a = *(const bf16x8s*)(&s_h[(m*16+lc)*LDH + ko]);
                pr[m]=mfma16(a,br,pr[m]); pz[m]=mfma16(a,bz,pz[m]); pn[m]=mfma16(a,bn,pn[m]);
            }
        }
        #pragma unroll
        for (int m=0;m<2;++m)
        #pragma unroll
        for (int i=0;i<4;++i){
            const int row = m*16 + quad*4 + i;
            float hp = bf2f(s_h[row*LDH + n]);
            float r  = sigmoidf(ar[m][i] + pr[m][i]);
            float z  = sigmoidf(az[m][i] + pz[m][i]);
            float nn = tanh_fast(an[m][i] + r*pn[m][i]);
            s_x[row*LDH + n] = f2bf((1.f - z)*nn + z*hp);
        }
    }
    __syncthreads();

    // ---- step6: final = GRU(intra@Wi + bi, inter@Wh + bh ; inter) -> s_fin
    #pragma unroll
    for (int g = wave; g < 8; g += 4) {
        const int n = g*16 + lc;
        const float vir = bi[n], viz = bi[128+n], vin = bi[256+n];
        const float vhr = bh[n], vhz = bh[128+n], vhn = bh[256+n];
        f32x4 ar[2], az[2], an[2], pr[2], pz[2], pn[2];
        #pragma unroll
        for (int m=0;m<2;++m){
            ar[m]=(f32x4){vir,vir,vir,vir}; az[m]=(f32x4){viz,viz,viz,viz}; an[m]=(f32x4){vin,vin,vin,vin};
            pr[m]=(f32x4){vhr,vhr,vhr,vhr}; pz[m]=(f32x4){vhz,vhz,vhz,vhz}; pn[m]=(f32x4){vhn,vhn,vhn,vhn};
        }
        #pragma unroll
        for (int ks=0; ks<4; ++ks) {
            const int ko = ks*32 + kq;
            bf16x8s br = *(const bf16x8s*)(WiT + (n      )*128 + ko);
            bf16x8s bz = *(const bf16x8s*)(WiT + (n + 128)*128 + ko);
            bf16x8s bn = *(const bf16x8s*)(WiT + (n + 256)*128 + ko);
            #pragma unroll
            for (int m=0;m<2;++m){
                bf16x8s a = *(const bf16x8s*)(&s_x[(m*16+lc)*LDH + ko]);
                ar[m]=mfma16(a,br,ar[m]); az[m]=mfma16(a,bz,az[m]); an[m]=mfma16(a,bn,an[m]);
            }
        }
        #pragma unroll
        for (int ks=0; ks<4; ++ks) {
            const int ko = ks*32 + kq;
            bf16x8s br = *(const bf16x8s*)(WhT + (n      )*128 + ko);
            bf16x8s bz = *(const bf16x8s*)(WhT + (n + 128)*128 + ko);
            bf16x8s bn = *(const bf16x8s*)(WhT + (n + 256)*128 + ko);
            #pragma unroll
            for (int m=0;m<2;++m){
                bf16x8s a = *(const bf16x8s*)(&s_int[(m*16+lc)*LDH + ko]);
                pr[m]=mfma16(a,br,pr[m]); pz[m]=mfma16(a,bz,pz[m]); pn[m]=mfma16(a,bn,pn[m]);
            }
        }
        #pragma unroll
        for (int m=0;m<2;++m)
        #pragma unroll
        for (int i=0;i<4;++i){
            const int row = m*16 + quad*4 + i;
            float hp = bf2f(s_int[row*LDH + n]);
            float r  = sigmoidf(ar[m][i] + pr[m][i]);
            float z  = sigmoidf(az[m][i] + pz[m][i]);
            float nn = tanh_fast(an[m][i] + r*pn[m][i]);
            s_fin[row*LDH + n] = f2bf((1.f - z)*nn + z*hp);
        }
    }
    __syncthreads();

    // ---- step7: attention readout
    const int slen = seq_len[b];
    if (t < DIM) s_vn[t] = bf2f(s_fin[(slen-1)*LDH + t]);
    __syncthreads();
    if (t < DIM) {                       // q1+b2 -> s_q1
        float acc = b1[t] + b2[t];
        #pragma unroll
        for (int k8=0; k8<16; ++k8) {
            union{ uint4 q; short s[8]; } u;
            u.q = *reinterpret_cast<const uint4*>(W1T + t*128 + k8*8);
            #pragma unroll
            for (int u2=0;u2<8;++u2) acc += s_vn[k8*8+u2]*bf2f(u.s[u2]);
        }
        s_q1[t] = acc;
    }
    __syncthreads();
    // final@W2 via MFMA; alpha partials
    #pragma unroll
    for (int tl = wave; tl < 16; tl += 4) {
        const int m0 = (tl & 1)*16, nt = tl >> 1;
        const int n  = nt*16 + lc;
        f32x4 acc = {0.f,0.f,0.f,0.f};
        #pragma unroll
        for (int ks=0; ks<4; ++ks) {
            const int ko = ks*32 + kq;
            bf16x8s a  = *(const bf16x8s*)(&s_fin[(m0+lc)*LDH + ko]);
            bf16x8s bb = *(const bf16x8s*)(W2T + n*128 + ko);
            acc = mfma16(a, bb, acc);
        }
        const float qb  = s_q1[n];
        const float wqv = wq[n];
        float p[4];
        #pragma unroll
        for (int i=0;i<4;++i) p[i] = sigmoidf(acc[i] + qb) * wqv;
        #pragma unroll
        for (int off=1; off<16; off<<=1) {
            #pragma unroll
            for (int i=0;i<4;++i) p[i] += __shfl_xor(p[i], off);
        }
        if (lc == 0) {
            #pragma unroll
            for (int i=0;i<4;++i) s_red[(m0+quad*4+i)*8 + nt] = p[i];
        }
    }
    __syncthreads();
    if (t < L_SEQ) {
        float al = bq[0];
        #pragma unroll
        for (int u=0;u<8;++u) al += s_red[t*8+u];
        s_alpha[t] = (t < slen) ? al : 0.f;
    }
    __syncthreads();
    if (t < DIM) {
        float sg = 0.f;
        #pragma unroll
        for (int l=0;l<L_SEQ;++l) sg += s_alpha[l]*bf2f(s_fin[l*LDH + t]);
        s_sg[t] = sg;
    }
    __syncthreads();
    if (t < DIM) {                       // h_s = concat(vn,sg)@W3 + b3 -> bf16
        float acc = b3[t];
        #pragma unroll
        for (int k8=0; k8<16; ++k8) {
            union{ uint4 q; short s[8]; } u;
            u.q = *reinterpret_cast<const uint4*>(W3T + t*256 + k8*8);
            #pragma unroll
            for (int u2=0;u2<8;++u2) acc += s_vn[k8*8+u2]*bf2f(u.s[u2]);
        }
        #pragma unroll
        for (int k8=0; k8<16; ++k8) {
            union{ uint4 q; short s[8]; } u;
            u.q = *reinterpret_cast<const uint4*>(W3T + t*256 + 128 + k8*8);
            #pragma unroll
            for (int u2=0;u2<8;++u2) acc += s_sg[k8*8+u2]*bf2f(u.s[u2]);
        }
        hs_bf[b*DIM + t] = f2bf(acc);
    }
}

// ---------- scores = h_s @ emb^T via MFMA; no LDS, no barriers ----------
__global__ __launch_bounds__(256)
void scores_kernel(const short* __restrict__ hs, const float* __restrict__ emb,
                   float* __restrict__ out)
{
    const int t    = threadIdx.x;
    const int wave = t >> 6;
    const int lane = t & 63;
    const int quad = lane >> 4;
    const int lc   = lane & 15;
    const int kq   = quad * 8;
    const int n0   = blockIdx.x * 64;
    const int m0   = blockIdx.y * 64 + wave*16;   // this wave's 16 rows

    bf16x8s af[4];
    #pragma unroll
    for (int ks=0; ks<4; ++ks)
        af[ks] = *(const bf16x8s*)(hs + (size_t)(m0 + lc)*DIM + ks*32 + kq);

    #pragma unroll
    for (int nt=0; nt<4; ++nt) {
        const int nabs = n0 + nt*16 + lc;
        const int nld  = nabs < NN ? nabs : NN-1;
        f32x4 acc = {0.f,0.f,0.f,0.f};
        #pragma unroll
        for (int ks=0; ks<4; ++ks) {
            float v[8]; ldf8(emb + (size_t)nld*DIM + ks*32 + kq, v);
            acc = mfma16(af[ks], cvt8(v), acc);
        }
        if (nabs < NN) {
            #pragma unroll
            for (int i=0;i<4;++i)
                out[(size_t)(m0 + quad*4 + i)*NN + nabs] = acc[i];
        }
    }
}

extern "C" void kernel_launch(void* const* d_in, const int* in_sizes, int n_in,
                              void* d_out, int out_size, void* d_ws, size_t ws_size,
                              hipStream_t stream)
{
    const int*   items   = (const int*)  d_in[0];
    const float* A_in    = (const float*)d_in[1];
    const float* A_out   = (const float*)d_in[2];
    const float* inter   = (const float*)d_in[3];
    const int*   seq_len = (const int*)  d_in[4];
    const float* emb     = (const float*)d_in[5];
    const float* W_in = (const float*)d_in[6],  *b_in  = (const float*)d_in[7];
    const float* W_out= (const float*)d_in[8],  *b_out = (const float*)d_in[9];
    const float* W_a  = (const float*)d_in[10], *U_h   = (const float*)d_in[11];
    const float* b_gru= (const float*)d_in[12];
    const float* Wi   = (const float*)d_in[13], *bi    = (const float*)d_in[14];
    const float* Wh   = (const float*)d_in[15], *bh    = (const float*)d_in[16];
    const float* W1   = (const float*)d_in[17], *b1    = (const float*)d_in[18];
    const float* W2   = (const float*)d_in[19], *b2    = (const float*)d_in[20];
    const float* wq   = (const float*)d_in[21], *bq    = (const float*)d_in[22];
    const float* W3   = (const float*)d_in[23], *b3    = (const float*)d_in[24];
    float* out = (float*)d_out;
    short* hs_bf = (short*)d_ws;                          // 1024*128 bf16 = 256 KB
    short* wt    = (short*)((char*)d_ws + 262144);        // 344064 bf16 = 688 KB

    transp_kernel<<<1344, 256, 0, stream>>>(W_in, W_out, W_a, U_h, Wi, Wh, W1, W2, W3, wt);
    graph_fused<<<1024, 256, 0, stream>>>(items, A_in, A_out, inter, seq_len, emb,
        b_in, b_out, b_gru, bi, bh, b1, b2, wq, bq, b3, wt, hs_bf);
    scores_kernel<<<dim3(782, 16), 256, 0, stream>>>(hs_bf, emb, out);
}